// Round 1
// baseline (1171.086 us; speedup 1.0000x reference)
//
#include <hip/hip_runtime.h>
#include <math.h>

#define A_NODES 50000
#define FEAT 128
#define EDGES 500000
#define NRBF 20
#define CUTOFF_F 5.0f
#define PI_OVER_CUTOFF 0.6283185307179586f

// ---------------------------------------------------------------------------
// Kernel 1: node-level scalar MLP: s = silu(scalars @ W1 + b1) @ W2 + b2
// 8 nodes per block, 128 threads. W elements loaded once, reused x8 in regs.
// ---------------------------------------------------------------------------
__global__ __launch_bounds__(128) void node_mlp_kernel(
    const float* __restrict__ scalars,
    const float* __restrict__ W1, const float* __restrict__ b1,
    const float* __restrict__ W2, const float* __restrict__ b2,
    float* __restrict__ s_tab)
{
    __shared__ float sc[8][128];
    __shared__ float hid[8][128];
    const int tx = threadIdx.x;
    const int base = blockIdx.x * 8;   // A_NODES = 50000 = 8 * 6250 exactly

    #pragma unroll
    for (int n = 0; n < 8; ++n)
        sc[n][tx] = scalars[(size_t)(base + n) * FEAT + tx];
    __syncthreads();

    // hidden = scalars @ W1 + b1
    float h[8];
    {
        const float bb = b1[tx];
        #pragma unroll
        for (int n = 0; n < 8; ++n) h[n] = bb;
    }
    #pragma unroll 4
    for (int k = 0; k < 128; ++k) {
        const float w = W1[k * 128 + tx];
        #pragma unroll
        for (int n = 0; n < 8; ++n) h[n] = fmaf(sc[n][k], w, h[n]);
    }
    // silu
    #pragma unroll
    for (int n = 0; n < 8; ++n) {
        const float x = h[n];
        hid[n][tx] = x / (1.0f + __expf(-x));
    }
    __syncthreads();

    // s = hid @ W2 + b2   (384 outputs: columns tx, tx+128, tx+256)
    float a0[8], a1[8], a2[8];
    {
        const float bb0 = b2[tx], bb1 = b2[tx + 128], bb2 = b2[tx + 256];
        #pragma unroll
        for (int n = 0; n < 8; ++n) { a0[n] = bb0; a1[n] = bb1; a2[n] = bb2; }
    }
    #pragma unroll 2
    for (int k = 0; k < 128; ++k) {
        const float w0 = W2[k * 384 + tx];
        const float w1 = W2[k * 384 + tx + 128];
        const float w2 = W2[k * 384 + tx + 256];
        #pragma unroll
        for (int n = 0; n < 8; ++n) {
            const float hh = hid[n][k];
            a0[n] = fmaf(hh, w0, a0[n]);
            a1[n] = fmaf(hh, w1, a1[n]);
            a2[n] = fmaf(hh, w2, a2[n]);
        }
    }
    #pragma unroll
    for (int n = 0; n < 8; ++n) {
        float* row = s_tab + (size_t)(base + n) * 384;
        row[tx]       = a0[n];
        row[tx + 128] = a1[n];
        row[tx + 256] = a2[n];
    }
}

// ---------------------------------------------------------------------------
// Kernel 2: per-edge radial + combine + scatter-add (atomics).
// 2 edges per 256-thread block; 128 threads per edge.
// ---------------------------------------------------------------------------
__global__ __launch_bounds__(256) void edge_kernel(
    const float* __restrict__ vectors,
    const float* __restrict__ directions,
    const int* __restrict__ idx_i, const int* __restrict__ idx_j,
    const float* __restrict__ Wr, const float* __restrict__ br,
    const float* __restrict__ s_tab,
    float* __restrict__ out_v, float* __restrict__ out_s)
{
    __shared__ float rbf[2][NRBF];
    __shared__ float fcs[2];

    const int tid = threadIdx.x & 127;
    const int es  = threadIdx.x >> 7;
    const long long e = (long long)blockIdx.x * 2 + es;  // EDGES even, exact

    const int i = idx_i[e];
    const int j = idx_j[e];

    const float d0 = directions[e * 3 + 0];
    const float d1 = directions[e * 3 + 1];
    const float d2 = directions[e * 3 + 2];
    const float nr = sqrtf(d0 * d0 + d1 * d1 + d2 * d2);
    const float invn = 1.0f / nr;

    if (tid < NRBF) {
        // fc = 0.5*(cos(pi*nr/c)+1) inside cutoff, 0 outside; fold fc into rbf
        const float fc = (nr < CUTOFF_F)
                       ? 0.5f * (cosf(PI_OVER_CUTOFF * nr) + 1.0f) : 0.0f;
        const float x = (float)(tid + 1) * PI_OVER_CUTOFF * nr;
        rbf[es][tid] = sinf(x) * invn * fc;
        if (tid == 0) fcs[es] = fc;
    }
    __syncthreads();

    const float fc = fcs[es];
    const int c0 = tid, c1 = tid + 128, c2 = tid + 256;

    // r = fc*(rbf @ Wr + br); fc already folded into rbf values
    float r0 = fc * br[c0], r1 = fc * br[c1], r2 = fc * br[c2];
    #pragma unroll
    for (int k = 0; k < NRBF; ++k) {
        const float rb = rbf[es][k];
        r0 = fmaf(rb, Wr[k * 384 + c0], r0);
        r1 = fmaf(rb, Wr[k * 384 + c1], r1);
        r2 = fmaf(rb, Wr[k * 384 + c2], r2);
    }

    const float* srow = s_tab + (size_t)i * 384;
    const float ds  = srow[c0] * r0;   // delta_s contribution
    const float dv1 = srow[c1] * r1;   // gate on vectors[idx_i]
    const float dv2 = srow[c2] * r2;   // gate on unit direction

    atomicAdd(&out_s[(size_t)j * 128 + tid], ds);

    const float u0 = d0 * invn, u1 = d1 * invn, u2 = d2 * invn;
    const float* vrow = vectors + (size_t)i * 384;
    const float vv0 = fmaf(vrow[tid],       dv1, dv2 * u0);
    const float vv1 = fmaf(vrow[128 + tid], dv1, dv2 * u1);
    const float vv2 = fmaf(vrow[256 + tid], dv1, dv2 * u2);

    float* ov = out_v + (size_t)j * 384;
    atomicAdd(&ov[tid],       vv0);
    atomicAdd(&ov[128 + tid], vv1);
    atomicAdd(&ov[256 + tid], vv2);
}

extern "C" void kernel_launch(void* const* d_in, const int* in_sizes, int n_in,
                              void* d_out, int out_size, void* d_ws, size_t ws_size,
                              hipStream_t stream) {
    const float* vectors    = (const float*)d_in[0];
    const float* scalars    = (const float*)d_in[1];
    const float* directions = (const float*)d_in[2];
    const int*   idx_i      = (const int*)d_in[3];
    const int*   idx_j      = (const int*)d_in[4];
    const float* W1         = (const float*)d_in[5];
    const float* b1         = (const float*)d_in[6];
    const float* W2         = (const float*)d_in[7];
    const float* b2         = (const float*)d_in[8];
    const float* Wr         = (const float*)d_in[9];
    const float* br         = (const float*)d_in[10];

    float* out_v = (float*)d_out;                         // (A,3,F) first
    float* out_s = out_v + (size_t)A_NODES * 3 * FEAT;    // then (A,1,F)
    float* s_tab = (float*)d_ws;                          // A x 384 fp32 = 76.8 MB

    // outputs are accumulated via atomics -> zero-init (harness poisons 0xAA)
    hipMemsetAsync(d_out, 0, (size_t)out_size * sizeof(float), stream);

    node_mlp_kernel<<<A_NODES / 8, 128, 0, stream>>>(scalars, W1, b1, W2, b2, s_tab);
    edge_kernel<<<EDGES / 2, 256, 0, stream>>>(vectors, directions, idx_i, idx_j,
                                               Wr, br, s_tab, out_v, out_s);
}

// Round 2
// 1015.310 us; speedup vs baseline: 1.1534x; 1.1534x over previous
//
#include <hip/hip_runtime.h>
#include <math.h>

#define A_NODES 50000
#define FEAT 128
#define EDGES 500000
#define NRBF 20
#define CUTOFF_F 5.0f
#define PI_OVER_CUTOFF 0.6283185307179586f

// ---------------------------------------------------------------------------
// Kernel 1: node-level scalar MLP: s = silu(scalars @ W1 + b1) @ W2 + b2
// 8 nodes per block, 128 threads. W elements loaded once, reused x8 in regs.
// ---------------------------------------------------------------------------
__global__ __launch_bounds__(128) void node_mlp_kernel(
    const float* __restrict__ scalars,
    const float* __restrict__ W1, const float* __restrict__ b1,
    const float* __restrict__ W2, const float* __restrict__ b2,
    float* __restrict__ s_tab)
{
    __shared__ float sc[8][128];
    __shared__ float hid[8][128];
    const int tx = threadIdx.x;
    const int base = blockIdx.x * 8;   // A_NODES = 50000 = 8 * 6250 exactly

    #pragma unroll
    for (int n = 0; n < 8; ++n)
        sc[n][tx] = scalars[(size_t)(base + n) * FEAT + tx];
    __syncthreads();

    float h[8];
    {
        const float bb = b1[tx];
        #pragma unroll
        for (int n = 0; n < 8; ++n) h[n] = bb;
    }
    #pragma unroll 4
    for (int k = 0; k < 128; ++k) {
        const float w = W1[k * 128 + tx];
        #pragma unroll
        for (int n = 0; n < 8; ++n) h[n] = fmaf(sc[n][k], w, h[n]);
    }
    #pragma unroll
    for (int n = 0; n < 8; ++n) {
        const float x = h[n];
        hid[n][tx] = x / (1.0f + __expf(-x));
    }
    __syncthreads();

    float a0[8], a1[8], a2[8];
    {
        const float bb0 = b2[tx], bb1 = b2[tx + 128], bb2 = b2[tx + 256];
        #pragma unroll
        for (int n = 0; n < 8; ++n) { a0[n] = bb0; a1[n] = bb1; a2[n] = bb2; }
    }
    #pragma unroll 2
    for (int k = 0; k < 128; ++k) {
        const float w0 = W2[k * 384 + tx];
        const float w1 = W2[k * 384 + tx + 128];
        const float w2 = W2[k * 384 + tx + 256];
        #pragma unroll
        for (int n = 0; n < 8; ++n) {
            const float hh = hid[n][k];
            a0[n] = fmaf(hh, w0, a0[n]);
            a1[n] = fmaf(hh, w1, a1[n]);
            a2[n] = fmaf(hh, w2, a2[n]);
        }
    }
    #pragma unroll
    for (int n = 0; n < 8; ++n) {
        float* row = s_tab + (size_t)(base + n) * 384;
        row[tx]       = a0[n];
        row[tx + 128] = a1[n];
        row[tx + 256] = a2[n];
    }
}

// ---------------------------------------------------------------------------
// CSR build: histogram of idx_j -> exclusive scan -> scatter edge ids.
// ---------------------------------------------------------------------------
__global__ __launch_bounds__(256) void hist_kernel(
    const int* __restrict__ idx_j, int* __restrict__ hist)
{
    const int e = blockIdx.x * 256 + threadIdx.x;
    if (e < EDGES) atomicAdd(&hist[idx_j[e]], 1);
}

__global__ __launch_bounds__(1024) void scan_kernel(
    const int* __restrict__ hist, int* __restrict__ offsets,
    int* __restrict__ cursor)
{
    __shared__ int part[1024];
    const int t = threadIdx.x;
    const int CH = (A_NODES + 1023) / 1024;   // 49
    const int base = t * CH;

    int sum = 0;
    for (int k = 0; k < CH; ++k) {
        const int idx = base + k;
        if (idx < A_NODES) sum += hist[idx];
    }
    part[t] = sum;
    __syncthreads();
    for (int off = 1; off < 1024; off <<= 1) {
        const int v = (t >= off) ? part[t - off] : 0;
        __syncthreads();
        part[t] += v;
        __syncthreads();
    }
    int run = part[t] - sum;   // exclusive prefix of this thread's chunk
    for (int k = 0; k < CH; ++k) {
        const int idx = base + k;
        if (idx < A_NODES) {
            offsets[idx] = run;
            cursor[idx]  = run;
            run += hist[idx];
        }
    }
    if (t == 0) offsets[A_NODES] = EDGES;
}

__global__ __launch_bounds__(256) void scatter_kernel(
    const int* __restrict__ idx_j, int* __restrict__ cursor,
    int* __restrict__ order)
{
    const int e = blockIdx.x * 256 + threadIdx.x;
    if (e < EDGES) {
        const int pos = atomicAdd(&cursor[idx_j[e]], 1);
        order[pos] = e;
    }
}

// ---------------------------------------------------------------------------
// Gather consumer: one wave per (node, half-of-128-cols). No atomics.
// Wr columns for this lane's 3 r-slots preloaded into 60 registers.
// rbf computed by lanes 0..19 (one sinf each), broadcast via __shfl.
// ---------------------------------------------------------------------------
__global__ __launch_bounds__(256) void gather_kernel(
    const float* __restrict__ vectors,
    const float* __restrict__ directions,
    const int* __restrict__ idx_i,
    const float* __restrict__ Wr, const float* __restrict__ br,
    const float* __restrict__ s_tab,
    const int* __restrict__ order, const int* __restrict__ offsets,
    float* __restrict__ out_v, float* __restrict__ out_s)
{
    const int lane = threadIdx.x & 63;
    const int w    = blockIdx.x * 4 + (threadIdx.x >> 6); // global wave id
    const int j    = w >> 1;            // node
    const int half = w & 1;             // which 64 of the 128 feature cols
    const int c    = half * 64 + lane;  // feature col in [0,128)

    // preload Wr columns (fixed per lane) into registers
    float wr0[NRBF], wr1[NRBF], wr2[NRBF];
    #pragma unroll
    for (int k = 0; k < NRBF; ++k) {
        const float* wrow = Wr + k * 384;
        wr0[k] = wrow[c];
        wr1[k] = wrow[128 + c];
        wr2[k] = wrow[256 + c];
    }
    const float b0 = br[c], b1 = br[128 + c], b2 = br[256 + c];

    const int beg = offsets[j];
    const int end = offsets[j + 1];

    float acc_s = 0.0f, acc_v0 = 0.0f, acc_v1 = 0.0f, acc_v2 = 0.0f;

    for (int p = beg; p < end; ++p) {
        const int e = order[p];
        const int i = idx_i[e];
        const float d0 = directions[(size_t)e * 3 + 0];
        const float d1 = directions[(size_t)e * 3 + 1];
        const float d2 = directions[(size_t)e * 3 + 2];
        const float nr   = sqrtf(d0 * d0 + d1 * d1 + d2 * d2);
        const float invn = 1.0f / nr;
        const float fc = (nr < CUTOFF_F)
                       ? 0.5f * (cosf(PI_OVER_CUTOFF * nr) + 1.0f) : 0.0f;

        // rbf_k * invn * fc, computed in lanes 0..19, broadcast via shfl
        float myrb = 0.0f;
        if (lane < NRBF)
            myrb = sinf((float)(lane + 1) * PI_OVER_CUTOFF * nr) * invn * fc;

        float rs = fc * b0, rv1 = fc * b1, rv2 = fc * b2;
        #pragma unroll
        for (int k = 0; k < NRBF; ++k) {
            const float rk = __shfl(myrb, k, 64);
            rs  = fmaf(rk, wr0[k], rs);
            rv1 = fmaf(rk, wr1[k], rv1);
            rv2 = fmaf(rk, wr2[k], rv2);
        }

        const float* srow = s_tab + (size_t)i * 384;
        acc_s = fmaf(srow[c], rs, acc_s);
        const float g1 = srow[128 + c] * rv1;   // gate on vectors[idx_i]
        const float g2 = srow[256 + c] * rv2;   // gate on unit direction

        const float u0 = d0 * invn, u1 = d1 * invn, u2 = d2 * invn;
        const float* vrow = vectors + (size_t)i * 384;
        acc_v0 = fmaf(vrow[c],       g1, fmaf(g2, u0, acc_v0));
        acc_v1 = fmaf(vrow[128 + c], g1, fmaf(g2, u1, acc_v1));
        acc_v2 = fmaf(vrow[256 + c], g1, fmaf(g2, u2, acc_v2));
    }

    out_s[(size_t)j * 128 + c] = acc_s;
    float* ov = out_v + (size_t)j * 384;
    ov[c]       = acc_v0;
    ov[128 + c] = acc_v1;
    ov[256 + c] = acc_v2;
}

extern "C" void kernel_launch(void* const* d_in, const int* in_sizes, int n_in,
                              void* d_out, int out_size, void* d_ws, size_t ws_size,
                              hipStream_t stream) {
    const float* vectors    = (const float*)d_in[0];
    const float* scalars    = (const float*)d_in[1];
    const float* directions = (const float*)d_in[2];
    const int*   idx_i      = (const int*)d_in[3];
    const int*   idx_j      = (const int*)d_in[4];
    const float* W1         = (const float*)d_in[5];
    const float* b1         = (const float*)d_in[6];
    const float* W2         = (const float*)d_in[7];
    const float* b2         = (const float*)d_in[8];
    const float* Wr         = (const float*)d_in[9];
    const float* br         = (const float*)d_in[10];

    float* out_v = (float*)d_out;                         // (A,3,F)
    float* out_s = out_v + (size_t)A_NODES * 3 * FEAT;    // (A,1,F)

    // workspace layout
    char* ws = (char*)d_ws;
    float* s_tab  = (float*)ws;                       ws += (size_t)A_NODES * 384 * 4; // 76.8 MB
    int* hist     = (int*)ws;                         ws += (size_t)A_NODES * 4;
    int* offsets  = (int*)ws;                         ws += (size_t)(A_NODES + 1) * 4;
    int* cursor   = (int*)ws;                         ws += (size_t)A_NODES * 4;
    int* order    = (int*)ws;                         ws += (size_t)EDGES * 4;

    hipMemsetAsync(hist, 0, (size_t)A_NODES * 4, stream);

    node_mlp_kernel<<<A_NODES / 8, 128, 0, stream>>>(scalars, W1, b1, W2, b2, s_tab);

    hist_kernel<<<(EDGES + 255) / 256, 256, 0, stream>>>(idx_j, hist);
    scan_kernel<<<1, 1024, 0, stream>>>(hist, offsets, cursor);
    scatter_kernel<<<(EDGES + 255) / 256, 256, 0, stream>>>(idx_j, cursor, order);

    gather_kernel<<<(A_NODES * 2) / 4, 256, 0, stream>>>(
        vectors, directions, idx_i, Wr, br, s_tab, order, offsets, out_v, out_s);
}

// Round 3
// 646.425 us; speedup vs baseline: 1.8116x; 1.5707x over previous
//
#include <hip/hip_runtime.h>
#include <math.h>

#define A_NODES 50000
#define FEAT 128
#define EDGES 500000
#define NRBF 20
#define CUTOFF_F 5.0f
#define PI_OVER_CUTOFF 0.6283185307179586f

typedef unsigned int uint32;
typedef unsigned short ushort16;

__device__ __forceinline__ ushort16 f2bf(float f) {
    union { float f; uint32 u; } v; v.f = f;
    uint32 r = (v.u + 0x7fffu + ((v.u >> 16) & 1u)) >> 16;   // RNE
    return (ushort16)r;
}
__device__ __forceinline__ uint32 packbf(float a, float b) {
    return (uint32)f2bf(a) | ((uint32)f2bf(b) << 16);
}
__device__ __forceinline__ float bf_lo(uint32 u) { return __uint_as_float(u << 16); }
__device__ __forceinline__ float bf_hi(uint32 u) { return __uint_as_float(u & 0xffff0000u); }

#if __has_builtin(__builtin_amdgcn_fdot2_f32_bf16)
typedef __bf16 bf16x2 __attribute__((ext_vector_type(2)));
__device__ __forceinline__ float dot2(uint32 a, uint32 b, float c) {
    return __builtin_amdgcn_fdot2_f32_bf16(
        __builtin_bit_cast(bf16x2, a), __builtin_bit_cast(bf16x2, b), c, false);
}
#else
__device__ __forceinline__ float dot2(uint32 a, uint32 b, float c) {
    return fmaf(bf_hi(a), bf_hi(b), fmaf(bf_lo(a), bf_lo(b), c));
}
#endif

// ---------------------------------------------------------------------------
// Kernel 1: node MLP -> s_tab stored as bf16
// ---------------------------------------------------------------------------
__global__ __launch_bounds__(128) void node_mlp_kernel(
    const float* __restrict__ scalars,
    const float* __restrict__ W1, const float* __restrict__ b1,
    const float* __restrict__ W2, const float* __restrict__ b2,
    ushort16* __restrict__ s_bf)
{
    __shared__ float sc[8][128];
    __shared__ float hid[8][128];
    const int tx = threadIdx.x;
    const int base = blockIdx.x * 8;

    #pragma unroll
    for (int n = 0; n < 8; ++n)
        sc[n][tx] = scalars[(size_t)(base + n) * FEAT + tx];
    __syncthreads();

    float h[8];
    {
        const float bb = b1[tx];
        #pragma unroll
        for (int n = 0; n < 8; ++n) h[n] = bb;
    }
    #pragma unroll 4
    for (int k = 0; k < 128; ++k) {
        const float w = W1[k * 128 + tx];
        #pragma unroll
        for (int n = 0; n < 8; ++n) h[n] = fmaf(sc[n][k], w, h[n]);
    }
    #pragma unroll
    for (int n = 0; n < 8; ++n) {
        const float x = h[n];
        hid[n][tx] = x / (1.0f + __expf(-x));
    }
    __syncthreads();

    float a0[8], a1[8], a2[8];
    {
        const float bb0 = b2[tx], bb1 = b2[tx + 128], bb2 = b2[tx + 256];
        #pragma unroll
        for (int n = 0; n < 8; ++n) { a0[n] = bb0; a1[n] = bb1; a2[n] = bb2; }
    }
    #pragma unroll 2
    for (int k = 0; k < 128; ++k) {
        const float w0 = W2[k * 384 + tx];
        const float w1 = W2[k * 384 + tx + 128];
        const float w2 = W2[k * 384 + tx + 256];
        #pragma unroll
        for (int n = 0; n < 8; ++n) {
            const float hh = hid[n][k];
            a0[n] = fmaf(hh, w0, a0[n]);
            a1[n] = fmaf(hh, w1, a1[n]);
            a2[n] = fmaf(hh, w2, a2[n]);
        }
    }
    #pragma unroll
    for (int n = 0; n < 8; ++n) {
        ushort16* row = s_bf + (size_t)(base + n) * 384;
        row[tx]       = f2bf(a0[n]);
        row[tx + 128] = f2bf(a1[n]);
        row[tx + 256] = f2bf(a2[n]);
    }
}

// ---------------------------------------------------------------------------
// vectors fp32 -> bf16 (packed pairs live as consecutive ushorts)
// ---------------------------------------------------------------------------
__global__ __launch_bounds__(256) void vec_cvt_kernel(
    const float* __restrict__ vin, uint32* __restrict__ vbf)
{
    const int t = blockIdx.x * 256 + threadIdx.x;   // pair index
    const size_t n2 = (size_t)A_NODES * 384 / 2;
    if (t < (int)n2) {
        const float a = vin[2 * (size_t)t];
        const float b = vin[2 * (size_t)t + 1];
        vbf[t] = packbf(a, b);
    }
}

// ---------------------------------------------------------------------------
// Pack Wr rows (2m,2m+1) into bf16x2 along k: wrpk[m*384+col]
// ---------------------------------------------------------------------------
__global__ __launch_bounds__(256) void wr_pack_kernel(
    const float* __restrict__ Wr, uint32* __restrict__ wrpk)
{
    const int t = blockIdx.x * 256 + threadIdx.x;
    if (t < 10 * 384) {
        const int m = t / 384, col = t % 384;
        wrpk[t] = packbf(Wr[(2 * m) * 384 + col], Wr[(2 * m + 1) * 384 + col]);
    }
}

// ---------------------------------------------------------------------------
// CSR build
// ---------------------------------------------------------------------------
__global__ __launch_bounds__(256) void hist_kernel(
    const int* __restrict__ idx_j, int* __restrict__ hist)
{
    const int e = blockIdx.x * 256 + threadIdx.x;
    if (e < EDGES) atomicAdd(&hist[idx_j[e]], 1);
}

__global__ __launch_bounds__(1024) void scan_kernel(
    const int* __restrict__ hist, int* __restrict__ offsets,
    int* __restrict__ cursor)
{
    __shared__ int part[1024];
    const int t = threadIdx.x;
    const int CH = (A_NODES + 1023) / 1024;

    int sum = 0;
    for (int k = 0; k < CH; ++k) {
        const int idx = t * CH + k;
        if (idx < A_NODES) sum += hist[idx];
    }
    part[t] = sum;
    __syncthreads();
    for (int off = 1; off < 1024; off <<= 1) {
        const int v = (t >= off) ? part[t - off] : 0;
        __syncthreads();
        part[t] += v;
        __syncthreads();
    }
    int run = part[t] - sum;
    for (int k = 0; k < CH; ++k) {
        const int idx = t * CH + k;
        if (idx < A_NODES) {
            offsets[idx] = run;
            cursor[idx]  = run;
            run += hist[idx];
        }
    }
    if (t == 0) offsets[A_NODES] = EDGES;
}

__global__ __launch_bounds__(256) void scatter_kernel(
    const int* __restrict__ idx_j, int* __restrict__ cursor,
    int* __restrict__ order)
{
    const int e = blockIdx.x * 256 + threadIdx.x;
    if (e < EDGES) {
        const int pos = atomicAdd(&cursor[idx_j[e]], 1);
        order[pos] = e;
    }
}

// ---------------------------------------------------------------------------
// Edge prep (CSR order): 16 dwords per position p:
//   [0..9]  rbf*invn*fc packed bf16x2 (k pairs)
//   [10..12] unit dir, [13] fc, [14] idx_i bits, [15] pad
// ---------------------------------------------------------------------------
__global__ __launch_bounds__(256) void edge_prep_kernel(
    const float* __restrict__ directions,
    const int* __restrict__ idx_i, const int* __restrict__ order,
    float* __restrict__ edata)
{
    const int p = blockIdx.x * 256 + threadIdx.x;
    if (p >= EDGES) return;
    const int e = order[p];
    const int i = idx_i[e];
    const float d0 = directions[(size_t)e * 3 + 0];
    const float d1 = directions[(size_t)e * 3 + 1];
    const float d2 = directions[(size_t)e * 3 + 2];
    const float nr   = sqrtf(d0 * d0 + d1 * d1 + d2 * d2);
    const float invn = 1.0f / nr;
    const float x = PI_OVER_CUTOFF * nr;
    float sx, cx;
    sincosf(x, &sx, &cx);
    const float fc = (nr < CUTOFF_F) ? 0.5f * (cx + 1.0f) : 0.0f;
    const float scale = invn * fc;
    const float twoc = 2.0f * cx;

    float out16[16];
    float s_odd = sx;      // sin((2m+1)x)
    float s_prev = 0.0f;   // sin(2m x)
    #pragma unroll
    for (int m = 0; m < 10; ++m) {
        const float s_even = twoc * s_odd - s_prev;       // sin((2m+2)x)
        out16[m] = __uint_as_float(packbf(s_odd * scale, s_even * scale));
        const float s_next = twoc * s_even - s_odd;       // sin((2m+3)x)
        s_prev = s_even;
        s_odd  = s_next;
    }
    out16[10] = d0 * invn;
    out16[11] = d1 * invn;
    out16[12] = d2 * invn;
    out16[13] = fc;
    out16[14] = __int_as_float(i);
    out16[15] = 0.0f;

    float4* dst = (float4*)(edata + (size_t)p * 16);
    dst[0] = make_float4(out16[0],  out16[1],  out16[2],  out16[3]);
    dst[1] = make_float4(out16[4],  out16[5],  out16[6],  out16[7]);
    dst[2] = make_float4(out16[8],  out16[9],  out16[10], out16[11]);
    dst[3] = make_float4(out16[12], out16[13], out16[14], out16[15]);
}

// ---------------------------------------------------------------------------
// Gather: block = 2 nodes x 2 parities; one wave per (node,parity);
// each lane owns cols 2*lane, 2*lane+1. No atomics, no per-edge sinf/shfl.
// ---------------------------------------------------------------------------
template <int VBF>
__global__ __launch_bounds__(256) void gather_kernel(
    const ushort16* __restrict__ s_bf,
    const ushort16* __restrict__ v_bf,
    const float* __restrict__ vectors_f32,
    const uint32* __restrict__ wrpk, const float* __restrict__ br,
    const float* __restrict__ edata,
    const int* __restrict__ offsets,
    float* __restrict__ out_v, float* __restrict__ out_s)
{
    const int lane   = threadIdx.x & 63;
    const int wv     = __builtin_amdgcn_readfirstlane(threadIdx.x >> 6);
    const int nsub   = wv >> 1;
    const int parity = wv & 1;
    const int j      = blockIdx.x * 2 + nsub;
    const int c0     = lane * 2;

    // preload packed Wr columns (fixed per lane): wA = col c0, wB = col c0+1
    uint32 wA[30], wB[30];
    #pragma unroll
    for (int s = 0; s < 3; ++s)
        #pragma unroll
        for (int m = 0; m < 10; ++m) {
            wA[s * 10 + m] = wrpk[m * 384 + s * 128 + c0];
            wB[s * 10 + m] = wrpk[m * 384 + s * 128 + c0 + 1];
        }
    const float brA0 = br[c0],       brB0 = br[c0 + 1];
    const float brA1 = br[128 + c0], brB1 = br[129 + c0];
    const float brA2 = br[256 + c0], brB2 = br[257 + c0];

    const int beg = offsets[j];
    const int end = offsets[j + 1];

    float accsA = 0.f, accsB = 0.f;
    float avA0 = 0.f, avA1 = 0.f, avA2 = 0.f;
    float avB0 = 0.f, avB1 = 0.f, avB2 = 0.f;

    for (int p = beg + parity; p < end; p += 2) {
        const float* ed = edata + (size_t)p * 16;   // wave-uniform -> s_load
        uint32 rb[10];
        #pragma unroll
        for (int m = 0; m < 10; ++m) rb[m] = __float_as_uint(ed[m]);
        const float u0 = ed[10], u1 = ed[11], u2 = ed[12], fcv = ed[13];
        const int   i  = __float_as_int(ed[14]);

        const ushort16* srow = s_bf + (size_t)i * 384;
        const uint32 s0 = *(const uint32*)(srow + c0);
        const uint32 s1 = *(const uint32*)(srow + 128 + c0);
        const uint32 s2 = *(const uint32*)(srow + 256 + c0);

        float rA0 = fcv * brA0, rA1 = fcv * brA1, rA2 = fcv * brA2;
        float rB0 = fcv * brB0, rB1 = fcv * brB1, rB2 = fcv * brB2;
        #pragma unroll
        for (int m = 0; m < 10; ++m) {
            const uint32 rm = rb[m];
            rA0 = dot2(rm, wA[m],      rA0);
            rA1 = dot2(rm, wA[10 + m], rA1);
            rA2 = dot2(rm, wA[20 + m], rA2);
            rB0 = dot2(rm, wB[m],      rB0);
            rB1 = dot2(rm, wB[10 + m], rB1);
            rB2 = dot2(rm, wB[20 + m], rB2);
        }

        const float sA0 = bf_lo(s0), sB0 = bf_hi(s0);
        const float sA1 = bf_lo(s1), sB1 = bf_hi(s1);
        const float sA2 = bf_lo(s2), sB2 = bf_hi(s2);

        accsA = fmaf(sA0, rA0, accsA);
        accsB = fmaf(sB0, rB0, accsB);
        const float gA1 = sA1 * rA1, gA2 = sA2 * rA2;
        const float gB1 = sB1 * rB1, gB2 = sB2 * rB2;

        float vA0, vB0, vA1, vB1, vA2, vB2;
        if (VBF) {
            const ushort16* vrow = v_bf + (size_t)i * 384;
            const uint32 v0 = *(const uint32*)(vrow + c0);
            const uint32 v1 = *(const uint32*)(vrow + 128 + c0);
            const uint32 v2 = *(const uint32*)(vrow + 256 + c0);
            vA0 = bf_lo(v0); vB0 = bf_hi(v0);
            vA1 = bf_lo(v1); vB1 = bf_hi(v1);
            vA2 = bf_lo(v2); vB2 = bf_hi(v2);
        } else {
            const float* vrow = vectors_f32 + (size_t)i * 384;
            vA0 = vrow[c0];       vB0 = vrow[c0 + 1];
            vA1 = vrow[128 + c0]; vB1 = vrow[129 + c0];
            vA2 = vrow[256 + c0]; vB2 = vrow[257 + c0];
        }

        avA0 = fmaf(vA0, gA1, fmaf(gA2, u0, avA0));
        avB0 = fmaf(vB0, gB1, fmaf(gB2, u0, avB0));
        avA1 = fmaf(vA1, gA1, fmaf(gA2, u1, avA1));
        avB1 = fmaf(vB1, gB1, fmaf(gB2, u1, avB1));
        avA2 = fmaf(vA2, gA1, fmaf(gA2, u2, avA2));
        avB2 = fmaf(vB2, gB1, fmaf(gB2, u2, avB2));
    }

    // combine the two parity waves per node via LDS
    __shared__ float red[4][64][9];
    float* slot = red[wv][lane];
    slot[0] = accsA; slot[1] = accsB;
    slot[2] = avA0;  slot[3] = avB0;
    slot[4] = avA1;  slot[5] = avB1;
    slot[6] = avA2;  slot[7] = avB2;
    __syncthreads();

    if (parity == 0) {
        const float* o = red[wv | 1][lane];
        float2* os = (float2*)(out_s + (size_t)j * 128 + c0);
        *os = make_float2(accsA + o[0], accsB + o[1]);
        float* ov = out_v + (size_t)j * 384;
        *(float2*)(ov + c0)       = make_float2(avA0 + o[2], avB0 + o[3]);
        *(float2*)(ov + 128 + c0) = make_float2(avA1 + o[4], avB1 + o[5]);
        *(float2*)(ov + 256 + c0) = make_float2(avA2 + o[6], avB2 + o[7]);
    }
}

extern "C" void kernel_launch(void* const* d_in, const int* in_sizes, int n_in,
                              void* d_out, int out_size, void* d_ws, size_t ws_size,
                              hipStream_t stream) {
    const float* vectors    = (const float*)d_in[0];
    const float* scalars    = (const float*)d_in[1];
    const float* directions = (const float*)d_in[2];
    const int*   idx_i      = (const int*)d_in[3];
    const int*   idx_j      = (const int*)d_in[4];
    const float* W1         = (const float*)d_in[5];
    const float* b1         = (const float*)d_in[6];
    const float* W2         = (const float*)d_in[7];
    const float* b2         = (const float*)d_in[8];
    const float* Wr         = (const float*)d_in[9];
    const float* br         = (const float*)d_in[10];

    float* out_v = (float*)d_out;
    float* out_s = out_v + (size_t)A_NODES * 3 * FEAT;

    // workspace layout (16B-aligned chunks)
    char* ws = (char*)d_ws;
    ushort16* s_bf = (ushort16*)ws;  ws += (size_t)A_NODES * 384 * 2;      // 38.4 MB
    float* edata   = (float*)ws;     ws += (size_t)EDGES * 16 * 4;         // 32.0 MB
    uint32* wrpk   = (uint32*)ws;    ws += (size_t)10 * 384 * 4;           // 15.4 KB
    int* hist      = (int*)ws;       ws += (size_t)A_NODES * 4;
    int* offsets   = (int*)ws;       ws += (((size_t)(A_NODES + 1) * 4 + 15) & ~(size_t)15);
    int* cursor    = (int*)ws;       ws += (size_t)A_NODES * 4;
    int* order     = (int*)ws;       ws += (size_t)EDGES * 4;
    ushort16* v_bf = (ushort16*)ws;  ws += (size_t)A_NODES * 384 * 2;      // 38.4 MB (optional)

    const int use_vbf = ((size_t)(ws - (char*)d_ws) <= ws_size) ? 1 : 0;

    hipMemsetAsync(hist, 0, (size_t)A_NODES * 4, stream);

    node_mlp_kernel<<<A_NODES / 8, 128, 0, stream>>>(scalars, W1, b1, W2, b2, s_bf);
    if (use_vbf)
        vec_cvt_kernel<<<(A_NODES * 384 / 2 + 255) / 256, 256, 0, stream>>>(vectors, (uint32*)v_bf);
    wr_pack_kernel<<<15, 256, 0, stream>>>(Wr, wrpk);

    hist_kernel<<<(EDGES + 255) / 256, 256, 0, stream>>>(idx_j, hist);
    scan_kernel<<<1, 1024, 0, stream>>>(hist, offsets, cursor);
    scatter_kernel<<<(EDGES + 255) / 256, 256, 0, stream>>>(idx_j, cursor, order);
    edge_prep_kernel<<<(EDGES + 255) / 256, 256, 0, stream>>>(directions, idx_i, order, edata);

    if (use_vbf)
        gather_kernel<1><<<A_NODES / 2, 256, 0, stream>>>(
            s_bf, v_bf, vectors, wrpk, br, edata, offsets, out_v, out_s);
    else
        gather_kernel<0><<<A_NODES / 2, 256, 0, stream>>>(
            s_bf, v_bf, vectors, wrpk, br, edata, offsets, out_v, out_s);
}